// Round 1
// baseline (468.561 us; speedup 1.0000x reference)
//
#include <hip/hip_runtime.h>
#include <math.h>

// Problem: P=20000, d=128, C=512, h=4. We assume d==128, h==4 (fixed dataset).
#define D_DIM 128
#define H_DIM 4

// ---------------- row norms of K (one wave per row) ----------------
__global__ void k_norm_rows(const float* __restrict__ K, float* __restrict__ rnK, int P) {
    int wavesPerBlock = blockDim.x >> 6;
    int wave = blockIdx.x * wavesPerBlock + (threadIdx.x >> 6);
    int lane = threadIdx.x & 63;
    if (wave >= P) return;
    const float* row = K + (size_t)wave * D_DIM;
    float v0 = row[lane], v1 = row[lane + 64];
    float ss = v0 * v0 + v1 * v1;
    #pragma unroll
    for (int off = 32; off > 0; off >>= 1) ss += __shfl_down(ss, off);
    if (lane == 0) {
        rnK[wave] = 1.0f / fmaxf(sqrtf(ss), 1e-12f);
    }
}

// ---------------- slot norms of Theta ----------------
__global__ void k_norm_theta(const float* __restrict__ Theta, float* __restrict__ rnT, int NJ) {
    int j = blockIdx.x * blockDim.x + threadIdx.x;
    if (j >= NJ) return;
    int c = j >> 2, s = j & 3;
    const float* base = Theta + (size_t)c * (D_DIM * H_DIM) + s;
    float ss = 0.f;
    #pragma unroll 8
    for (int k = 0; k < D_DIM; k++) { float v = base[k * H_DIM]; ss += v * v; }
    rnT[j] = 1.0f / fmaxf(sqrtf(ss), 1e-12f);
}

// ---------------- build normalized-transposed K: KnT[k][p], zero-padded ----------------
__global__ void k_build_knt(const float* __restrict__ K, const float* __restrict__ rnK,
                            float* __restrict__ KnT, int P, int Ppad) {
    int p = blockIdx.x * blockDim.x + threadIdx.x;
    if (p >= Ppad) return;
    if (p < P) {
        float rn = rnK[p];
        const float* row = K + (size_t)p * D_DIM;
        #pragma unroll 8
        for (int k = 0; k < D_DIM; k++) KnT[(size_t)k * Ppad + p] = row[k] * rn;
    } else {
        #pragma unroll 8
        for (int k = 0; k < D_DIM; k++) KnT[(size_t)k * Ppad + p] = 0.f;
    }
}

// ---------------- build normalized-transposed Theta: TnT[k][j], j=c*4+s ----------------
__global__ void k_build_tnt(const float* __restrict__ Theta, const float* __restrict__ rnT,
                            float* __restrict__ TnT, int NJ) {
    int j = blockIdx.x * blockDim.x + threadIdx.x;
    if (j >= NJ) return;
    int c = j >> 2, s = j & 3;
    float rn = rnT[j];
    const float* base = Theta + (size_t)c * (D_DIM * H_DIM) + s;
    #pragma unroll 8
    for (int k = 0; k < D_DIM; k++) TnT[(size_t)k * NJ + j] = base[k * H_DIM] * rn;
}

// ---------------- fused GEMM + per-column (over p) max/argmax, per p-tile ----------------
#define BP 128
#define BJ 128
#define BK 64

__global__ __launch_bounds__(256) void k_gemm_argmax(
    const float* __restrict__ KnT, const float* __restrict__ TnT,
    float* __restrict__ pval, int* __restrict__ pidx,
    int P, int Ppad, int NJ)
{
    __shared__ float ldsA[BK * BP];  // [kk][p_local]  32 KB
    __shared__ float ldsB[BK * BJ];  // [kk][j_local]  32 KB

    int tid = threadIdx.x;
    int tx = tid & 15, ty = tid >> 4;
    int j0 = blockIdx.x * BJ;
    int p0 = blockIdx.y * BP;

    float acc[8][8];
    #pragma unroll
    for (int i = 0; i < 8; i++)
        #pragma unroll
        for (int j = 0; j < 8; j++) acc[i][j] = 0.f;

    for (int k0 = 0; k0 < D_DIM; k0 += BK) {
        // stage A and B tiles: 2048 float4 each, 8 per thread
        #pragma unroll
        for (int i = 0; i < 8; i++) {
            int f = tid + i * 256;
            int kk = f >> 5, r4 = f & 31;
            *(float4*)&ldsA[kk * BP + r4 * 4] =
                *(const float4*)&KnT[(size_t)(k0 + kk) * Ppad + p0 + r4 * 4];
            *(float4*)&ldsB[kk * BJ + r4 * 4] =
                *(const float4*)&TnT[(size_t)(k0 + kk) * NJ + j0 + r4 * 4];
        }
        __syncthreads();
        #pragma unroll 8
        for (int kk = 0; kk < BK; kk++) {
            float4 a0 = *(float4*)&ldsA[kk * BP + ty * 8];
            float4 a1 = *(float4*)&ldsA[kk * BP + ty * 8 + 4];
            float4 b0 = *(float4*)&ldsB[kk * BJ + tx * 8];
            float4 b1 = *(float4*)&ldsB[kk * BJ + tx * 8 + 4];
            float a[8] = {a0.x, a0.y, a0.z, a0.w, a1.x, a1.y, a1.z, a1.w};
            float b[8] = {b0.x, b0.y, b0.z, b0.w, b1.x, b1.y, b1.z, b1.w};
            #pragma unroll
            for (int i = 0; i < 8; i++)
                #pragma unroll
                for (int j = 0; j < 8; j++)
                    acc[i][j] = fmaf(a[i], b[j], acc[i][j]);
        }
        __syncthreads();
    }

    // local column max over this thread's 8 rows (rows = p0 + ty*8 + i)
    float lmax[8]; int lidx[8];
    #pragma unroll
    for (int j = 0; j < 8; j++) { lmax[j] = -INFINITY; lidx[j] = 0x7fffffff; }
    #pragma unroll
    for (int i = 0; i < 8; i++) {
        int p = p0 + ty * 8 + i;
        bool ok = (p < P);
        #pragma unroll
        for (int j = 0; j < 8; j++) {
            float v = ok ? acc[i][j] : -INFINITY;
            if (v > lmax[j]) { lmax[j] = v; lidx[j] = p; }  // ascending i => first-max kept
        }
    }
    __syncthreads();
    // cross-ty reduce via LDS (reuse tiles)
    float* rv = ldsA;           // [16][128]
    int*   ri = (int*)ldsB;     // [16][128]
    #pragma unroll
    for (int j = 0; j < 8; j++) {
        rv[ty * BJ + tx * 8 + j] = lmax[j];
        ri[ty * BJ + tx * 8 + j] = lidx[j];
    }
    __syncthreads();
    if (tid < BJ) {
        float bv = -INFINITY; int bi = 0x7fffffff;
        #pragma unroll 4
        for (int t = 0; t < 16; t++) {
            float v = rv[t * BJ + tid];
            int  ix = ri[t * BJ + tid];
            if (v > bv || (v == bv && ix < bi)) { bv = v; bi = ix; }
        }
        pval[(size_t)blockIdx.y * NJ + j0 + tid] = bv;
        pidx[(size_t)blockIdx.y * NJ + j0 + tid] = bi;
    }
}

// ---------------- reduce partial max/argmax across p-tiles ----------------
__global__ void k_reduce(const float* __restrict__ pval, const int* __restrict__ pidx,
                         float* __restrict__ conf, int* __restrict__ best, int NJ, int TP) {
    int j = blockIdx.x * blockDim.x + threadIdx.x;
    if (j >= NJ) return;
    float bv = -INFINITY; int bi = 0x7fffffff;
    for (int t = 0; t < TP; t++) {
        float v = pval[(size_t)t * NJ + j];
        int  ix = pidx[(size_t)t * NJ + j];
        if (v > bv || (v == bv && ix < bi)) { bv = v; bi = ix; }
    }
    conf[j] = bv; best[j] = bi;
}

// ---------------- copy initial_val -> out ----------------
__global__ void k_copy(const float* __restrict__ a, float* __restrict__ o, int n) {
    int i = blockIdx.x * blockDim.x + threadIdx.x;
    if (i < n) o[i] = a[i];
}

// ---------------- the 6-iteration soft-logic loop, single block ----------------
__global__ __launch_bounds__(1024) void k_logic(
    const int* __restrict__ head_idx, const float* __restrict__ initial_val,
    const float* __restrict__ conf, const int* __restrict__ best,
    float* __restrict__ out, int C)
{
    __shared__ int   hidx[1024];
    __shared__ int   slot[1024];
    __shared__ float hval[1024];
    __shared__ float elds[1024];

    int c = threadIdx.x;  // blockDim.x == C
    hidx[c] = head_idx[c];
    __syncthreads();

    int h = hidx[c];
    int myslot = c;
    for (int t = 0; t < C; t++) { if (hidx[t] == h) { myslot = t; break; } }
    slot[c] = myslot;
    hval[c] = initial_val[h];
    __syncthreads();

    float cf[H_DIM], v0[H_DIM]; int bs[H_DIM];
    #pragma unroll
    for (int s = 0; s < H_DIM; s++) {
        int b = best[c * H_DIM + s];
        cf[s] = conf[c * H_DIM + s];
        v0[s] = initial_val[b];
        bs[s] = -1;
        for (int t = 0; t < C; t++) { if (hidx[t] == b) { bs[s] = slot[t]; break; } }
    }

    const float inv_tau = 20.0f;           // 1/TAU
    const float logn = logf(2.0f * H_DIM); // log 8
    const float beta = 8.0f;

    for (int it = 0; it < 6; it++) {
        // reads of hval + zero elds
        float x[2 * H_DIM];
        #pragma unroll
        for (int s = 0; s < H_DIM; s++) {
            x[s] = cf[s];
            x[H_DIM + s] = (bs[s] >= 0) ? hval[bs[s]] : v0[s];
        }
        float cur = hval[myslot];
        elds[c] = 0.f;
        __syncthreads();

        float m = x[0];
        #pragma unroll
        for (int i = 1; i < 2 * H_DIM; i++) m = fminf(m, x[i]);
        float ssum = 0.f;
        #pragma unroll
        for (int i = 0; i < 2 * H_DIM; i++) ssum += expf((m - x[i]) * inv_tau);
        // lse(-x/tau) = -m/tau + log(ssum);  g = -(1/tau)*(lse - log n)
        float g = -inv_tau * ((-m * inv_tau + logf(ssum)) - logn);
        g = fminf(fmaxf(g, 0.f), 1.f);
        float w = expf(beta * g);
        atomicAdd(&elds[myslot], w);
        __syncthreads();

        float e = elds[myslot];
        float gh = logf(fmaxf(e, 1e-38f)) / beta;
        float nv = fmaxf(cur, gh);   // e > 0 always at head positions
        if (myslot == c) hval[c] = nv;
        __syncthreads();
    }

    if (myslot == c) out[h] = hval[c];
}

// ---------------- launch ----------------
extern "C" void kernel_launch(void* const* d_in, const int* in_sizes, int n_in,
                              void* d_out, int out_size, void* d_ws, size_t ws_size,
                              hipStream_t stream) {
    const float* K          = (const float*)d_in[0];
    const float* Theta      = (const float*)d_in[1];
    const int*   head_idx   = (const int*)d_in[2];
    const float* initial    = (const float*)d_in[3];
    float* out = (float*)d_out;

    int P  = in_sizes[3];
    int C  = in_sizes[2];
    int NJ = C * H_DIM;                    // 2048
    int Ppad = ((P + BP - 1) / BP) * BP;   // 20096
    int TP = Ppad / BP;                    // 157

    // workspace carve-up (256-B aligned)
    char* w = (char*)d_ws;
    size_t off = 0;
    auto alloc = [&](size_t bytes) { void* p = w + off; off += (bytes + 255) & ~(size_t)255; return p; };
    float* rnK  = (float*)alloc((size_t)P * 4);
    float* rnT  = (float*)alloc((size_t)NJ * 4);
    float* KnT  = (float*)alloc((size_t)D_DIM * Ppad * 4);
    float* TnT  = (float*)alloc((size_t)D_DIM * NJ * 4);
    float* pv   = (float*)alloc((size_t)TP * NJ * 4);
    int*   pi   = (int*)alloc((size_t)TP * NJ * 4);
    float* conf = (float*)alloc((size_t)NJ * 4);
    int*   best = (int*)alloc((size_t)NJ * 4);
    (void)ws_size;

    k_norm_rows<<<(P + 3) / 4, 256, 0, stream>>>(K, rnK, P);
    k_norm_theta<<<(NJ + 255) / 256, 256, 0, stream>>>(Theta, rnT, NJ);
    k_build_knt<<<(Ppad + 255) / 256, 256, 0, stream>>>(K, rnK, KnT, P, Ppad);
    k_build_tnt<<<(NJ + 255) / 256, 256, 0, stream>>>(Theta, rnT, TnT, NJ);

    dim3 grid(NJ / BJ, TP);
    k_gemm_argmax<<<grid, 256, 0, stream>>>(KnT, TnT, pv, pi, P, Ppad, NJ);

    k_reduce<<<(NJ + 255) / 256, 256, 0, stream>>>(pv, pi, conf, best, NJ, TP);
    k_copy<<<(P + 255) / 256, 256, 0, stream>>>(initial, out, P);
    k_logic<<<1, C, 0, stream>>>(head_idx, initial, conf, best, out, C);
}

// Round 2
// 126.356 us; speedup vs baseline: 3.7083x; 3.7083x over previous
//
#include <hip/hip_runtime.h>
#include <hip/hip_bf16.h>
#include <math.h>

// Problem: P=20000, d=128, C=512, h=4 (fixed dataset). d==128, h==4 assumed.
#define D_DIM 128
#define H_DIM 4

typedef __attribute__((ext_vector_type(4))) float f32x4;
typedef __attribute__((ext_vector_type(8))) __bf16 bf16x8v;

__device__ inline unsigned short f2bf(float f) {
    __hip_bfloat16 b = __float2bfloat16(f);
    return *reinterpret_cast<unsigned short*>(&b);
}

// ---- build normalized K rows in bf16 (row-major [Ppad][128]) + 1/norm ----
__global__ __launch_bounds__(256) void k_knb(
    const float* __restrict__ K, unsigned int* __restrict__ Knb,
    float* __restrict__ rnK, int P, int Ppad)
{
    int row = blockIdx.x * 4 + (threadIdx.x >> 6);
    int lane = threadIdx.x & 63;
    if (row >= Ppad) return;
    if (row >= P) { Knb[(size_t)row * 64 + lane] = 0u; return; }
    float2 v = ((const float2*)(K + (size_t)row * D_DIM))[lane];
    float ss = v.x * v.x + v.y * v.y;
    #pragma unroll
    for (int off = 1; off < 64; off <<= 1) ss += __shfl_xor(ss, off);
    float rn = 1.0f / fmaxf(sqrtf(ss), 1e-12f);
    unsigned int pk = (unsigned)f2bf(v.x * rn) | ((unsigned)f2bf(v.y * rn) << 16);
    Knb[(size_t)row * 64 + lane] = pk;
    if (lane == 0) rnK[row] = rn;
}

// ---- build normalized Theta rows: bf16 [NJ][128] and fp32 [NJ][128] ----
__global__ __launch_bounds__(256) void k_tn(
    const float* __restrict__ Theta, unsigned int* __restrict__ Tnb,
    float* __restrict__ Tn32, int NJ)
{
    int j = blockIdx.x * 4 + (threadIdx.x >> 6);
    int lane = threadIdx.x & 63;
    if (j >= NJ) return;
    int c = j >> 2, s = j & 3;
    const float* base = Theta + (size_t)c * (D_DIM * H_DIM) + s;
    float t0 = base[(2 * lane) * H_DIM];
    float t1 = base[(2 * lane + 1) * H_DIM];
    float ss = t0 * t0 + t1 * t1;
    #pragma unroll
    for (int off = 1; off < 64; off <<= 1) ss += __shfl_xor(ss, off);
    float rn = 1.0f / fmaxf(sqrtf(ss), 1e-12f);
    float n0 = t0 * rn, n1 = t1 * rn;
    Tnb[(size_t)j * 64 + lane] = (unsigned)f2bf(n0) | ((unsigned)f2bf(n1) << 16);
    float2 w; w.x = n0; w.y = n1;
    ((float2*)(Tn32 + (size_t)j * D_DIM))[lane] = w;
}

// ---- head_of scatter: head_of[head_idx[c]] = min c ----
__global__ void k_scatter(const int* __restrict__ head_idx, int* __restrict__ head_of, int C) {
    int c = blockIdx.x * blockDim.x + threadIdx.x;
    if (c < C) atomicMin(&head_of[head_idx[c]], c);
}

// ---- bf16 MFMA GEMM, fused per-(j, 128p-tile) max.  D[j][p]=Tn·Kn^T ----
// block: 256 thr = 4 waves (2x2), tile 128j x 128p, K=128 in one LDS stage.
__global__ __launch_bounds__(256) void k_mfma_max(
    const unsigned short* __restrict__ Knb, const unsigned short* __restrict__ Tnb,
    float* __restrict__ pv, int NT)
{
    __shared__ __align__(16) unsigned short As[128 * 128];  // Tn tile  32 KB
    __shared__ __align__(16) unsigned short Bs[128 * 128];  // Kn tile  32 KB

    int tid = threadIdx.x;
    int p0 = blockIdx.x * 128, j0 = blockIdx.y * 128;

    // stage with XOR swizzle on 16B chunks: chunk' = chunk ^ (row&7)
    {
        int c = tid & 15;
        int r0 = tid >> 4;
        const unsigned short* gA = Tnb + (size_t)j0 * 128;
        const unsigned short* gB = Knb + (size_t)p0 * 128;
        #pragma unroll
        for (int i = 0; i < 8; i++) {
            int r = r0 + 16 * i;
            int src = r * 128 + 8 * c;
            int dst = r * 128 + ((8 * c) ^ ((r & 7) << 3));
            *(bf16x8v*)&As[dst] = *(const bf16x8v*)&gA[src];
            *(bf16x8v*)&Bs[dst] = *(const bf16x8v*)&gB[src];
        }
    }
    __syncthreads();

    int lane = tid & 63;
    int wave = tid >> 6;
    int wm = wave >> 1, wn = wave & 1;
    int lr = lane & 15, lg = lane >> 4;

    f32x4 acc[4][4];
    #pragma unroll
    for (int m = 0; m < 4; m++)
        #pragma unroll
        for (int n = 0; n < 4; n++) { f32x4 z = {0.f, 0.f, 0.f, 0.f}; acc[m][n] = z; }

    #pragma unroll
    for (int ks = 0; ks < 4; ks++) {
        int koff = (8 * lg + 32 * ks) ^ ((lr & 7) << 3);
        bf16x8v af[4], bv[4];
        #pragma unroll
        for (int m = 0; m < 4; m++) {
            int row = 64 * wm + 16 * m + lr;
            af[m] = *(const bf16x8v*)&As[row * 128 + koff];
        }
        #pragma unroll
        for (int n = 0; n < 4; n++) {
            int row = 64 * wn + 16 * n + lr;
            bv[n] = *(const bf16x8v*)&Bs[row * 128 + koff];
        }
        #pragma unroll
        for (int m = 0; m < 4; m++)
            #pragma unroll
            for (int n = 0; n < 4; n++)
                acc[m][n] = __builtin_amdgcn_mfma_f32_16x16x32_bf16(af[m], bv[n], acc[m][n], 0, 0, 0);
    }

    // epilogue: max over p.  C/D: col(p)=lane&15, row(j)=4*(lane>>4)+reg
    float vm[4][4];
    #pragma unroll
    for (int m = 0; m < 4; m++)
        #pragma unroll
        for (int r = 0; r < 4; r++)
            vm[m][r] = fmaxf(fmaxf(acc[m][0][r], acc[m][1][r]),
                             fmaxf(acc[m][2][r], acc[m][3][r]));
    #pragma unroll
    for (int off = 1; off <= 8; off <<= 1)
        #pragma unroll
        for (int m = 0; m < 4; m++)
            #pragma unroll
            for (int r = 0; r < 4; r++)
                vm[m][r] = fmaxf(vm[m][r], __shfl_xor(vm[m][r], off));

    __syncthreads();
    float* red = (float*)As;   // [128][2]
    if (lr == 0) {
        #pragma unroll
        for (int m = 0; m < 4; m++)
            #pragma unroll
            for (int r = 0; r < 4; r++)
                red[(64 * wm + 16 * m + 4 * lg + r) * 2 + wn] = vm[m][r];
    }
    __syncthreads();
    if (tid < 128)
        pv[(size_t)(j0 + tid) * NT + blockIdx.x] = fmaxf(red[tid * 2], red[tid * 2 + 1]);
}

// ---- exact fp32 rescore of candidate tiles (within 2*eps of bf16 max) ----
__global__ __launch_bounds__(256) void k_rescore(
    const float* __restrict__ pv, const float* __restrict__ K,
    const float* __restrict__ rnK, const float* __restrict__ Tn32,
    float* __restrict__ conf, int* __restrict__ best, int P, int NT)
{
    __shared__ float tn[4][D_DIM];
    int wave = threadIdx.x >> 6, lane = threadIdx.x & 63;
    int j = blockIdx.x * 4 + wave;

    float2 t2 = ((const float2*)(Tn32 + (size_t)j * D_DIM))[lane];
    ((float2*)tn[wave])[lane] = t2;
    __syncthreads();

    const float* pvj = pv + (size_t)j * NT;
    float m1 = -INFINITY;
    for (int t = lane; t < NT; t += 64) m1 = fmaxf(m1, pvj[t]);
    #pragma unroll
    for (int off = 32; off; off >>= 1) m1 = fmaxf(m1, __shfl_xor(m1, off));
    float thr = m1 - 0.009f;   // 2*eps, eps<=0.0045 for bf16-rounded unit vectors

    float bvv = -INFINITY; int bp = 0x7fffffff;
    for (int t = 0; t < NT; t++) {
        if (pvj[t] < thr) continue;
        #pragma unroll
        for (int q = 0; q < 2; q++) {
            int p = t * 128 + 64 * q + lane;
            if (p >= P) continue;
            const float4* kp = (const float4*)(K + (size_t)p * D_DIM);
            const float4* tp = (const float4*)tn[wave];
            float sx = 0.f, sy = 0.f, sz = 0.f, sw = 0.f;
            #pragma unroll 8
            for (int k4 = 0; k4 < D_DIM / 4; k4++) {
                float4 a = kp[k4];
                float4 b = tp[k4];
                sx = fmaf(a.x, b.x, sx); sy = fmaf(a.y, b.y, sy);
                sz = fmaf(a.z, b.z, sz); sw = fmaf(a.w, b.w, sw);
            }
            float v = ((sx + sy) + (sz + sw)) * rnK[p];
            if (v > bvv || (v == bvv && p < bp)) { bvv = v; bp = p; }
        }
    }
    #pragma unroll
    for (int off = 32; off; off >>= 1) {
        float ov = __shfl_xor(bvv, off);
        int op = __shfl_xor(bp, off);
        if (ov > bvv || (ov == bvv && op < bp)) { bvv = ov; bp = op; }
    }
    if (lane == 0) { conf[j] = bvv; best[j] = bp; }
}

// ---- copy initial_val -> out ----
__global__ void k_copy(const float* __restrict__ a, float* __restrict__ o, int n) {
    int i = blockIdx.x * blockDim.x + threadIdx.x;
    if (i < n) o[i] = a[i];
}

// ---- 6-iteration soft-logic loop, single block, O(1) setup via head_of ----
__global__ __launch_bounds__(1024) void k_logic(
    const int* __restrict__ head_idx, const float* __restrict__ initial_val,
    const float* __restrict__ conf, const int* __restrict__ best,
    const int* __restrict__ head_of,
    float* __restrict__ out, int C)
{
    __shared__ float hval[1024];
    __shared__ float elds[1024];
    int c = threadIdx.x;   // blockDim.x == C
    int h = head_idx[c];
    int myslot = head_of[h];           // min clause index sharing this head
    hval[c] = initial_val[h];

    float cf[H_DIM], v0[H_DIM]; int bs[H_DIM];
    #pragma unroll
    for (int s = 0; s < H_DIM; s++) {
        int b = best[c * H_DIM + s];
        cf[s] = conf[c * H_DIM + s];
        v0[s] = initial_val[b];
        int ho = head_of[b];
        bs[s] = (ho < C) ? ho : -1;    // sentinel 0x7f7f7f7f if b not a head
    }
    __syncthreads();

    const float inv_tau = 20.0f;            // 1/TAU
    const float logn = logf(2.0f * H_DIM);  // log 8
    const float beta = 8.0f;

    for (int it = 0; it < 6; it++) {
        float x[2 * H_DIM];
        #pragma unroll
        for (int s = 0; s < H_DIM; s++) {
            x[s] = cf[s];
            x[H_DIM + s] = (bs[s] >= 0) ? hval[bs[s]] : v0[s];
        }
        float cur = hval[myslot];
        elds[c] = 0.f;
        __syncthreads();

        float m = x[0];
        #pragma unroll
        for (int i = 1; i < 2 * H_DIM; i++) m = fminf(m, x[i]);
        float ssum = 0.f;
        #pragma unroll
        for (int i = 0; i < 2 * H_DIM; i++) ssum += expf((m - x[i]) * inv_tau);
        float g = -inv_tau * ((-m * inv_tau + logf(ssum)) - logn);
        g = fminf(fmaxf(g, 0.f), 1.f);
        float w = expf(beta * g);
        atomicAdd(&elds[myslot], w);
        __syncthreads();

        float e = elds[myslot];
        float gh = logf(fmaxf(e, 1e-38f)) / beta;
        float nv = fmaxf(cur, gh);
        if (myslot == c) hval[c] = nv;
        __syncthreads();
    }

    if (myslot == c) out[h] = hval[c];
}

// ---------------- launch ----------------
extern "C" void kernel_launch(void* const* d_in, const int* in_sizes, int n_in,
                              void* d_out, int out_size, void* d_ws, size_t ws_size,
                              hipStream_t stream) {
    const float* K        = (const float*)d_in[0];
    const float* Theta    = (const float*)d_in[1];
    const int*   head_idx = (const int*)d_in[2];
    const float* initial  = (const float*)d_in[3];
    float* out = (float*)d_out;

    int P  = in_sizes[3];
    int C  = in_sizes[2];
    int NJ = C * H_DIM;                     // 2048
    int Ppad = ((P + 127) / 128) * 128;     // 20096 -> pad to 128; here 20096? (20000->20096? no: 157*128=20096) -> NT
    int NT = Ppad / 128;

    char* w = (char*)d_ws;
    size_t off = 0;
    auto alloc = [&](size_t bytes) { void* p = w + off; off += (bytes + 255) & ~(size_t)255; return p; };
    unsigned int* Knb  = (unsigned int*)alloc((size_t)Ppad * D_DIM * 2);
    unsigned int* Tnb  = (unsigned int*)alloc((size_t)NJ * D_DIM * 2);
    float* Tn32 = (float*)alloc((size_t)NJ * D_DIM * 4);
    float* rnK  = (float*)alloc((size_t)P * 4);
    float* pv   = (float*)alloc((size_t)NJ * NT * 4);
    float* conf = (float*)alloc((size_t)NJ * 4);
    int*   best = (int*)alloc((size_t)NJ * 4);
    int*   head_of = (int*)alloc((size_t)P * 4);
    (void)ws_size;

    hipMemsetAsync(head_of, 0x7F, (size_t)P * 4, stream);   // "infinity" sentinel
    k_scatter<<<(C + 255) / 256, 256, 0, stream>>>(head_idx, head_of, C);
    k_knb<<<(Ppad + 3) / 4, 256, 0, stream>>>(K, Knb, rnK, P, Ppad);
    k_tn<<<(NJ + 3) / 4, 256, 0, stream>>>(Theta, Tnb, Tn32, NJ);

    dim3 grid(NT, NJ / 128);
    k_mfma_max<<<grid, 256, 0, stream>>>((const unsigned short*)Knb,
                                         (const unsigned short*)Tnb, pv, NT);

    k_rescore<<<NJ / 4, 256, 0, stream>>>(pv, K, rnK, Tn32, conf, best, P, NT);
    k_copy<<<(P + 255) / 256, 256, 0, stream>>>(initial, out, P);
    k_logic<<<1, C, 0, stream>>>(head_idx, initial, conf, best, head_of, out, C);
}